// Round 12
// baseline (219.534 us; speedup 1.0000x reference)
//
#include <hip/hip_runtime.h>
#include <math.h>

#define N_NODES 50000
#define N_EDGES 600000
#define DF 128
#define KK 256
#define DOUT 40
#define EPSN 1e-5f
#define NB1 196  // ceil(50000/256)

typedef __attribute__((ext_vector_type(8))) short sh8;   // 8 bf16 (4 VGPRs)
typedef __attribute__((ext_vector_type(4))) float f32x4;

__device__ __forceinline__ unsigned short f2b(float f) {  // fp32 -> bf16 RNE
  unsigned u = __builtin_bit_cast(unsigned, f);
  unsigned r = u + 0x7FFFu + ((u >> 16) & 1u);
  return (unsigned short)(r >> 16);
}
__device__ __forceinline__ float b2f(unsigned short b) {
  unsigned u = ((unsigned)b) << 16;
  return __builtin_bit_cast(float, u);
}
__device__ __forceinline__ float gelu_f(float x) {
  return 0.5f * x * (1.0f + erff(x * 0.70710678118654752f));
}

// ---------------------------------------------------------------------------
// Fused prep: [0,2344) edge-count atomics | [2344,14844) cvt_x -> X0 compact |
// rest: weights in CHUNK-MAJOR layout for coalesced B-frag loads.
// ---------------------------------------------------------------------------
__global__ __launch_bounds__(256) void k_prep(
    const int* __restrict__ ei, int* __restrict__ counts,
    const float* __restrict__ x, unsigned* __restrict__ X0u,
    const float* __restrict__ Wl0, const float* __restrict__ Wr0,
    const float* __restrict__ Wl1, const float* __restrict__ Wr1,
    const float* __restrict__ Wl2, const float* __restrict__ Wr2,
    unsigned short* __restrict__ WT0, unsigned short* __restrict__ WT1,
    unsigned short* __restrict__ WT2b) {
  const int b = blockIdx.x, t = threadIdx.x;
  if (b < 2344) {
    int e = b * 256 + t;
    if (e < N_EDGES) atomicAdd(&counts[ei[N_EDGES + e]], 1);
  } else if (b < 14844) {
    int i = (b - 2344) * 256 + t;  // < 3,200,000 exact
    float2 v = ((const float2*)x)[i];
    X0u[i] = (unsigned)f2b(v.x) | ((unsigned)f2b(v.y) << 16);
  } else {
    int i = (b - 14844) * 256 + t;  // < 75776
    if (i >= 75776) return;
    if (i < 65536) {
      const float* Wl; const float* Wr; unsigned short* WT; int j;
      if (i < 32768) { j = i;         Wl = Wl0; Wr = Wr0; WT = WT0; }
      else           { j = i - 32768; Wl = Wl1; Wr = Wr1; WT = WT1; }
      int n = j >> 8, k = j & 255;
      float v = (k < DF) ? Wl[k * DF + n] : Wr[(k - DF) * DF + n];
      WT[(k >> 3) * 1024 + n * 8 + (k & 7)] = f2b(v);
    } else {
      int j = i - 65536;               // 0..10239
      int n = j >> 7, k = j & 127;     // n<80, k<128
      float v = (n < DOUT) ? Wl2[k * DOUT + n] : Wr2[k * DOUT + (n - DOUT)];
      WT2b[(k >> 3) * 640 + n * 8 + (k & 7)] = f2b(v);
    }
  }
}

// ---------------------------------------------------------------------------
// Scan (single stage): block b sums counts[0..256b) itself, then block-local
// exclusive scan -> rowptr/cursor/invdeg.
// ---------------------------------------------------------------------------
__global__ __launch_bounds__(256) void k_rowptr(
    const int* __restrict__ counts,
    int* __restrict__ rowptr, int* __restrict__ cursor,
    float* __restrict__ invdeg) {
  const int t = threadIdx.x;
  const int lane = t & 63, w = t >> 6;
  __shared__ int wtot[4], wpre[4];

  int pre = 0;
  const int limit = blockIdx.x * 256;
  for (int i = t; i < limit; i += 256) pre += counts[i];
  #pragma unroll
  for (int m = 1; m < 64; m <<= 1) pre += __shfl_xor(pre, m);
  if (lane == 0) wpre[w] = pre;

  const int i = blockIdx.x * 256 + t;
  int c = (i < N_NODES) ? counts[i] : 0;
  int s = c;
  #pragma unroll
  for (int off = 1; off < 64; off <<= 1) {
    int u = __shfl_up(s, off);
    if (lane >= off) s += u;
  }
  if (lane == 63) wtot[w] = s;
  __syncthreads();
  int add = wpre[0] + wpre[1] + wpre[2] + wpre[3];
  for (int k = 0; k < w; ++k) add += wtot[k];
  if (i < N_NODES) {
    int excl = s - c + add;
    rowptr[i] = excl;
    cursor[i] = excl;
    invdeg[i] = 1.0f / (float)((c > 1) ? c : 1);
  }
  if (blockIdx.x == 0 && t == 0) rowptr[N_NODES] = N_EDGES;
}

__global__ __launch_bounds__(256) void k_fill(
    const int* __restrict__ ei, int* __restrict__ cursor, int* __restrict__ csr) {
  int e = blockIdx.x * 256 + threadIdx.x;
  if (e < N_EDGES) {
    int d = ei[N_EDGES + e];
    int p = atomicAdd(&cursor[d], 1);
    csr[p] = ei[e];
  }
}

// ---------------------------------------------------------------------------
// FUSED SAGE layer: gather-mean straight into LDS A-tile + MFMA + LN + GELU.
// Grid 3125 x 16 rows. Each wave gathers 4 nodes in PARALLEL (16-lane
// subgroups, same issue structure as the standalone k_agg: 12500 gather
// waves, 8 outstanding loads each). X ping-pong: compact [50000][128] bf16.
// ---------------------------------------------------------------------------
__global__ __launch_bounds__(256) void k_sage128(
    const unsigned short* __restrict__ Xsrc, const unsigned short* __restrict__ WT,
    const float* __restrict__ bl, const float* __restrict__ g,
    const float* __restrict__ be,
    const int* __restrict__ rowptr, const int* __restrict__ csr,
    const float* __restrict__ invdeg, unsigned short* __restrict__ Xdst) {
  __shared__ __align__(16) char lds[8704];      // 8KB A-tile + 512B partials
  unsigned short* olds = (unsigned short*)lds;  // out-stage [16][136] (reuse)
  float2* pp = (float2*)(lds + 8192);           // [4 waves][16 rows] (s, sq)

  const int t = threadIdx.x;
  const int rw = blockIdx.x * 16;
  const int wave = t >> 6, lane = t & 63;
  const int lr = lane & 15, lg = lane >> 4;

  // --- own-x staging: 16 rows x 256B, coalesced, into x-half of tile ---
  {
    int r = t >> 4, c = t & 15;
    sh8 v = *(const sh8*)(Xsrc + (size_t)(rw + r) * DF + c * 8);
    unsigned off = (unsigned)((r * 512 + 256 + c * 16) ^ ((r & 7) << 4));
    *(sh8*)(lds + off) = v;
  }

  // --- gather-mean: wave w -> rows 4w..4w+3, one 16-lane subgroup each ---
  {
    const int sg = lane >> 4, l = lane & 15;
    const int r = wave * 4 + sg;
    const int node = rw + r;
    const int beg = rowptr[node], end = rowptr[node + 1];
    const uint4* X4 = (const uint4*)Xsrc;  // row pitch 16 uint4

    float f0=0,f1=0,f2=0,f3=0,f4=0,f5=0,f6=0,f7=0;
    float g0=0,g1=0,g2=0,g3=0,g4=0,g5=0,g6=0,g7=0;
    int j = beg;
    for (; j + 2 <= end; j += 2) {
      int c0 = csr[j], c1 = csr[j + 1];
      uint4 p = X4[(size_t)c0 * 16 + l];
      uint4 q = X4[(size_t)c1 * 16 + l];
      f0 += b2f((unsigned short)p.x); f1 += b2f((unsigned short)(p.x >> 16));
      f2 += b2f((unsigned short)p.y); f3 += b2f((unsigned short)(p.y >> 16));
      f4 += b2f((unsigned short)p.z); f5 += b2f((unsigned short)(p.z >> 16));
      f6 += b2f((unsigned short)p.w); f7 += b2f((unsigned short)(p.w >> 16));
      g0 += b2f((unsigned short)q.x); g1 += b2f((unsigned short)(q.x >> 16));
      g2 += b2f((unsigned short)q.y); g3 += b2f((unsigned short)(q.y >> 16));
      g4 += b2f((unsigned short)q.z); g5 += b2f((unsigned short)(q.z >> 16));
      g6 += b2f((unsigned short)q.w); g7 += b2f((unsigned short)(q.w >> 16));
    }
    if (j < end) {
      uint4 p = X4[(size_t)csr[j] * 16 + l];
      f0 += b2f((unsigned short)p.x); f1 += b2f((unsigned short)(p.x >> 16));
      f2 += b2f((unsigned short)p.y); f3 += b2f((unsigned short)(p.y >> 16));
      f4 += b2f((unsigned short)p.z); f5 += b2f((unsigned short)(p.z >> 16));
      f6 += b2f((unsigned short)p.w); f7 += b2f((unsigned short)(p.w >> 16));
    }
    f0+=g0; f1+=g1; f2+=g2; f3+=g3; f4+=g4; f5+=g5; f6+=g6; f7+=g7;
    const float rd = invdeg[node];
    uint4 o;
    o.x = (unsigned)f2b(f0 * rd) | ((unsigned)f2b(f1 * rd) << 16);
    o.y = (unsigned)f2b(f2 * rd) | ((unsigned)f2b(f3 * rd) << 16);
    o.z = (unsigned)f2b(f4 * rd) | ((unsigned)f2b(f5 * rd) << 16);
    o.w = (unsigned)f2b(f6 * rd) | ((unsigned)f2b(f7 * rd) << 16);
    *(uint4*)(lds + ((unsigned)(r * 512 + l * 16) ^ ((r & 7) << 4))) = o;
  }

  // --- B fragments (after gather to keep gather-phase VGPR pressure low) ---
  sh8 Bfrag[2][8];
  {
    const sh8* Bp = (const sh8*)WT;  // [32 chunks][128 n]
    #pragma unroll
    for (int fl = 0; fl < 2; ++fl) {
      const int n = wave * 32 + fl * 16 + lr;
      #pragma unroll
      for (int ks = 0; ks < 8; ++ks) Bfrag[fl][ks] = Bp[(ks * 4 + lg) * 128 + n];
    }
  }
  const int col0 = wave * 32 + lr, col1 = col0 + 16;
  const float bc0 = bl[col0], bc1 = bl[col1];
  const float gv0 = g[col0], gv1 = g[col1];
  const float bev0 = be[col0], bev1 = be[col1];

  __syncthreads();

  f32x4 acc0 = {0.f, 0.f, 0.f, 0.f}, acc1 = {0.f, 0.f, 0.f, 0.f};
  #pragma unroll
  for (int ks = 0; ks < 8; ++ks) {
    unsigned off = (unsigned)((lr * 512 + ks * 64 + lg * 16) ^ ((lr & 7) << 4));
    sh8 a = *(const sh8*)(lds + off);
    acc0 = __builtin_amdgcn_mfma_f32_16x16x32_bf16(a, Bfrag[0][ks], acc0, 0, 0, 0);
    acc1 = __builtin_amdgcn_mfma_f32_16x16x32_bf16(a, Bfrag[1][ks], acc1, 0, 0, 0);
  }

  float sv[4], qv[4];
  #pragma unroll
  for (int r = 0; r < 4; ++r) {
    float v0 = acc0[r] + bc0, v1 = acc1[r] + bc1;
    acc0[r] = v0; acc1[r] = v1;
    sv[r] = v0 + v1; qv[r] = v0 * v0 + v1 * v1;
  }
  #pragma unroll
  for (int m = 1; m < 16; m <<= 1) {
    #pragma unroll
    for (int r = 0; r < 4; ++r) {
      sv[r] += __shfl_xor(sv[r], m);
      qv[r] += __shfl_xor(qv[r], m);
    }
  }
  if (lr == 0) {
    #pragma unroll
    for (int r = 0; r < 4; ++r)
      pp[wave * 16 + lg * 4 + r] = make_float2(sv[r], qv[r]);
  }
  __syncthreads();

  #pragma unroll
  for (int r = 0; r < 4; ++r) {
    const int row = lg * 4 + r;
    float2 a0 = pp[row], a1 = pp[16 + row], a2 = pp[32 + row], a3 = pp[48 + row];
    float mu = (a0.x + a1.x + a2.x + a3.x) * (1.0f / 128.0f);
    float var = (a0.y + a1.y + a2.y + a3.y) * (1.0f / 128.0f) - mu * mu;
    float rs = rsqrtf(var + EPSN);
    float xn0 = (acc0[r] - mu) * rs * gv0 + bev0;
    float xn1 = (acc1[r] - mu) * rs * gv1 + bev1;
    olds[row * 136 + col0] = f2b(gelu_f(xn0));
    olds[row * 136 + col1] = f2b(gelu_f(xn1));
  }
  __syncthreads();

  {
    int r = t >> 4, c = t & 15;
    sh8 v = *(const sh8*)((char*)olds + r * 272 + c * 16);
    *(sh8*)(Xdst + (size_t)(rw + r) * DF + c * 8) = v;
  }
}

// ---------------------------------------------------------------------------
// Layer-2 projection: PQ = h1 @ [Wl2|Wr2]  ([50000x128] @ [128x80], bf16 out).
// Stages from compact X; B coalesced via chunk-major WT2b.
// ---------------------------------------------------------------------------
__global__ __launch_bounds__(256) void k_gemm80(
    const unsigned short* __restrict__ X, const unsigned short* __restrict__ WT2b,
    unsigned short* __restrict__ PQ) {
  __shared__ __align__(16) char lds[16384];
  const int t = threadIdx.x;
  const int rw = blockIdx.x * 64;
  const int wave = t >> 6, lane = t & 63;
  const int lr = lane & 15, lg = lane >> 4;

  #pragma unroll
  for (int it = 0; it < 4; ++it) {
    int id = it * 256 + t;
    int r = id >> 4, c = id & 15;
    int gr = rw + r; if (gr >= N_NODES) gr = N_NODES - 1;
    sh8 v = *(const sh8*)(X + (size_t)gr * DF + c * 8);
    unsigned off = (unsigned)((r * 256 + c * 16) ^ ((r & 7) << 4));
    *(sh8*)(lds + off) = v;
  }

  sh8 Bfrag[5][4];
  {
    const sh8* Bp = (const sh8*)WT2b;  // [16 chunks][80 n]
    #pragma unroll
    for (int f = 0; f < 5; ++f) {
      const int n = f * 16 + lr;
      #pragma unroll
      for (int ks = 0; ks < 4; ++ks) Bfrag[f][ks] = Bp[(ks * 4 + lg) * 80 + n];
    }
  }
  __syncthreads();

  f32x4 accs[5];
  #pragma unroll
  for (int f = 0; f < 5; ++f) accs[f] = (f32x4){0.f, 0.f, 0.f, 0.f};

  #pragma unroll
  for (int ks = 0; ks < 4; ++ks) {
    const int r = wave * 16 + lr;
    unsigned off = (unsigned)((r * 256 + ks * 64 + lg * 16) ^ ((r & 7) << 4));
    sh8 a = *(const sh8*)(lds + off);
    #pragma unroll
    for (int f = 0; f < 5; ++f)
      accs[f] = __builtin_amdgcn_mfma_f32_16x16x32_bf16(a, Bfrag[f][ks], accs[f], 0, 0, 0);
  }
  __syncthreads();

  unsigned short* olds = (unsigned short*)lds;
  #pragma unroll
  for (int f = 0; f < 5; ++f) {
    #pragma unroll
    for (int r = 0; r < 4; ++r) {
      const int row = wave * 16 + lg * 4 + r;
      olds[row * 80 + f * 16 + lr] = f2b(accs[f][r]);
    }
  }
  __syncthreads();

  #pragma unroll
  for (int it = 0; it < 3; ++it) {
    int id = it * 256 + t;
    if (id < 640) {
      int r = (id * 6554) >> 16;   // id / 10
      int c = id - r * 10;
      int gr = rw + r;
      if (gr < N_NODES)
        *(sh8*)(PQ + (size_t)gr * 80 + c * 8) =
            *(const sh8*)((char*)olds + r * 160 + c * 16);
    }
  }
}

// ---------------------------------------------------------------------------
// Final: per node, mean-gather P (40 dims) + Q + bias, log_softmax -> out.
// ---------------------------------------------------------------------------
__global__ __launch_bounds__(256) void k_final(
    const unsigned short* __restrict__ PQ, const float* __restrict__ bl,
    const int* __restrict__ rowptr, const int* __restrict__ csr,
    const float* __restrict__ invdeg, float* __restrict__ out) {
  const int node = blockIdx.x * 8 + (threadIdx.x >> 5);
  const int hl = threadIdx.x & 31;
  const bool act = (hl < 20);
  const int l = act ? hl : 0;
  const unsigned* Pu = (const unsigned*)PQ;  // row pitch 40 uints

  const int beg = rowptr[node], end = rowptr[node + 1];
  float ax = 0.f, ay = 0.f, bx = 0.f, by = 0.f;
  float cx = 0.f, cy = 0.f, dx = 0.f, dy = 0.f;
  int j = beg;
  for (; j + 4 <= end; j += 4) {
    int c0 = csr[j], c1 = csr[j + 1], c2 = csr[j + 2], c3 = csr[j + 3];
    unsigned p0 = Pu[(size_t)c0 * 40 + l];
    unsigned p1 = Pu[(size_t)c1 * 40 + l];
    unsigned p2 = Pu[(size_t)c2 * 40 + l];
    unsigned p3 = Pu[(size_t)c3 * 40 + l];
    ax += b2f((unsigned short)p0); ay += b2f((unsigned short)(p0 >> 16));
    bx += b2f((unsigned short)p1); by += b2f((unsigned short)(p1 >> 16));
    cx += b2f((unsigned short)p2); cy += b2f((unsigned short)(p2 >> 16));
    dx += b2f((unsigned short)p3); dy += b2f((unsigned short)(p3 >> 16));
  }
  for (; j < end; ++j) {
    unsigned p = Pu[(size_t)csr[j] * 40 + l];
    ax += b2f((unsigned short)p); ay += b2f((unsigned short)(p >> 16));
  }
  ax += bx + cx + dx;
  ay += by + cy + dy;
  const float rd = invdeg[node];
  unsigned q = Pu[(size_t)node * 40 + 20 + l];
  float v0 = ax * rd + b2f((unsigned short)q) + bl[2 * l];
  float v1 = ay * rd + b2f((unsigned short)(q >> 16)) + bl[2 * l + 1];

  float m = act ? fmaxf(v0, v1) : -INFINITY;
  #pragma unroll
  for (int k = 1; k < 32; k <<= 1) m = fmaxf(m, __shfl_xor(m, k));
  float se = act ? (expf(v0 - m) + expf(v1 - m)) : 0.0f;
  #pragma unroll
  for (int k = 1; k < 32; k <<= 1) se += __shfl_xor(se, k);
  float lse = m + logf(se);
  if (act)
    ((float2*)out)[(size_t)node * 20 + hl] = make_float2(v0 - lse, v1 - lse);
}

// ---------------------------------------------------------------------------
extern "C" void kernel_launch(void* const* d_in, const int* in_sizes, int n_in,
                              void* d_out, int out_size, void* d_ws, size_t ws_size,
                              hipStream_t stream) {
  const float* x   = (const float*)d_in[0];
  const int*   ei  = (const int*)d_in[1];
  const float* Wl0 = (const float*)d_in[2];
  const float* bl0 = (const float*)d_in[3];
  const float* Wr0 = (const float*)d_in[4];
  const float* Wl1 = (const float*)d_in[5];
  const float* bl1 = (const float*)d_in[6];
  const float* Wr1 = (const float*)d_in[7];
  const float* Wl2 = (const float*)d_in[8];
  const float* bl2 = (const float*)d_in[9];
  const float* Wr2 = (const float*)d_in[10];
  const float* g0  = (const float*)d_in[11];
  const float* be0 = (const float*)d_in[12];
  const float* g1  = (const float*)d_in[13];
  const float* be1 = (const float*)d_in[14];
  float* out = (float*)d_out;

  unsigned short* X0   = (unsigned short*)d_ws;       // 50000*128 bf16 (12.8MB)
  unsigned short* X1   = X0 + (size_t)N_NODES * DF;   // 50000*128 bf16
  unsigned short* PQ   = X1 + (size_t)N_NODES * DF;   // 50000*80 bf16 (8MB)
  unsigned short* WT0  = PQ + (size_t)N_NODES * 80;   // 128*256
  unsigned short* WT1  = WT0 + 128 * KK;              // 128*256
  unsigned short* WT2b = WT1 + 128 * KK;              // 80*128
  float* invdeg = (float*)(WT2b + 80 * 128);          // 50000
  int*   counts = (int*)(invdeg + N_NODES);           // 50000
  int*   rowptr = counts + N_NODES;                   // 50001
  int*   cursor = rowptr + N_NODES + 1;               // 50000
  int*   csr    = cursor + N_NODES;                   // 600000

  const int egrid = (N_EDGES + 255) / 256;    // 2344
  const int pgrid = 2344 + 12500 + 296;       // 15140
  const int sgrid = N_NODES / 16;             // 3125
  const int g80   = (N_NODES + 63) / 64;      // 782
  const int fgrid = N_NODES / 8;              // 6250

  // --- CSR build + converts ---
  hipMemsetAsync(counts, 0, N_NODES * sizeof(int), stream);
  k_prep<<<pgrid, 256, 0, stream>>>(ei, counts, x, (unsigned*)X0,
                                    Wl0, Wr0, Wl1, Wr1, Wl2, Wr2,
                                    WT0, WT1, WT2b);
  k_rowptr<<<NB1, 256, 0, stream>>>(counts, rowptr, cursor, invdeg);
  k_fill<<<egrid, 256, 0, stream>>>(ei, cursor, csr);

  // --- Fused layers (ping-pong X0 -> X1 -> X0) ---
  k_sage128<<<sgrid, 256, 0, stream>>>(X0, WT0, bl0, g0, be0, rowptr, csr, invdeg, X1);
  k_sage128<<<sgrid, 256, 0, stream>>>(X1, WT1, bl1, g1, be1, rowptr, csr, invdeg, X0);

  // --- Layer 2 (project to 40+40 dims, then gather in 40-dim space) ---
  k_gemm80<<<g80, 256, 0, stream>>>(X0, WT2b, PQ);
  k_final<<<fgrid, 256, 0, stream>>>(PQ, bl2, rowptr, csr, invdeg, out);
}

// Round 13
// 215.024 us; speedup vs baseline: 1.0210x; 1.0210x over previous
//
#include <hip/hip_runtime.h>
#include <math.h>

#define N_NODES 50000
#define N_EDGES 600000
#define DF 128
#define KK 256
#define DOUT 40
#define EPSN 1e-5f
#define NB1 196  // ceil(50000/256)

typedef __attribute__((ext_vector_type(8))) short sh8;   // 8 bf16 (4 VGPRs)
typedef __attribute__((ext_vector_type(4))) float f32x4;

__device__ __forceinline__ unsigned short f2b(float f) {  // fp32 -> bf16 RNE
  unsigned u = __builtin_bit_cast(unsigned, f);
  unsigned r = u + 0x7FFFu + ((u >> 16) & 1u);
  return (unsigned short)(r >> 16);
}
__device__ __forceinline__ float b2f(unsigned short b) {
  unsigned u = ((unsigned)b) << 16;
  return __builtin_bit_cast(float, u);
}
__device__ __forceinline__ float gelu_f(float x) {
  return 0.5f * x * (1.0f + erff(x * 0.70710678118654752f));
}

#define ACC8(S, P) do { \
  S[0] += b2f((unsigned short)(P).x); S[1] += b2f((unsigned short)((P).x >> 16)); \
  S[2] += b2f((unsigned short)(P).y); S[3] += b2f((unsigned short)((P).y >> 16)); \
  S[4] += b2f((unsigned short)(P).z); S[5] += b2f((unsigned short)((P).z >> 16)); \
  S[6] += b2f((unsigned short)(P).w); S[7] += b2f((unsigned short)((P).w >> 16)); } while (0)

// ---------------------------------------------------------------------------
// Fused prep: [0,2344) edge-count atomics | [2344,14844) cvt_x -> x-half of A |
// rest: weights in CHUNK-MAJOR layout for coalesced B-frag loads.
// ---------------------------------------------------------------------------
__global__ __launch_bounds__(256) void k_prep(
    const int* __restrict__ ei, int* __restrict__ counts,
    const float* __restrict__ x, unsigned* __restrict__ A,
    const float* __restrict__ Wl0, const float* __restrict__ Wr0,
    const float* __restrict__ Wl1, const float* __restrict__ Wr1,
    const float* __restrict__ Wl2, const float* __restrict__ Wr2,
    unsigned short* __restrict__ WT0, unsigned short* __restrict__ WT1,
    unsigned short* __restrict__ WT2b) {
  const int b = blockIdx.x, t = threadIdx.x;
  if (b < 2344) {
    int e = b * 256 + t;
    if (e < N_EDGES) atomicAdd(&counts[ei[N_EDGES + e]], 1);
  } else if (b < 14844) {
    int i = (b - 2344) * 256 + t;  // < 3,200,000 exact
    int n = i >> 6, p = i & 63;
    float2 v = ((const float2*)x)[i];
    A[(size_t)n * 128 + 64 + p] = (unsigned)f2b(v.x) | ((unsigned)f2b(v.y) << 16);
  } else {
    int i = (b - 14844) * 256 + t;  // < 75776
    if (i >= 75776) return;
    if (i < 65536) {
      const float* Wl; const float* Wr; unsigned short* WT; int j;
      if (i < 32768) { j = i;         Wl = Wl0; Wr = Wr0; WT = WT0; }
      else           { j = i - 32768; Wl = Wl1; Wr = Wr1; WT = WT1; }
      int n = j >> 8, k = j & 255;
      float v = (k < DF) ? Wl[k * DF + n] : Wr[(k - DF) * DF + n];
      WT[(k >> 3) * 1024 + n * 8 + (k & 7)] = f2b(v);
    } else {
      int j = i - 65536;               // 0..10239
      int n = j >> 7, k = j & 127;     // n<80, k<128
      float v = (n < DOUT) ? Wl2[k * DOUT + n] : Wr2[k * DOUT + (n - DOUT)];
      WT2b[(k >> 3) * 640 + n * 8 + (k & 7)] = f2b(v);
    }
  }
}

// ---------------------------------------------------------------------------
// Scan (single stage): block b sums counts[0..256b) itself, then block-local
// exclusive scan -> rowptr/cursor/invdeg.
// ---------------------------------------------------------------------------
__global__ __launch_bounds__(256) void k_rowptr(
    const int* __restrict__ counts,
    int* __restrict__ rowptr, int* __restrict__ cursor,
    float* __restrict__ invdeg) {
  const int t = threadIdx.x;
  const int lane = t & 63, w = t >> 6;
  __shared__ int wtot[4], wpre[4];

  int pre = 0;
  const int limit = blockIdx.x * 256;
  for (int i = t; i < limit; i += 256) pre += counts[i];
  #pragma unroll
  for (int m = 1; m < 64; m <<= 1) pre += __shfl_xor(pre, m);
  if (lane == 0) wpre[w] = pre;

  const int i = blockIdx.x * 256 + t;
  int c = (i < N_NODES) ? counts[i] : 0;
  int s = c;
  #pragma unroll
  for (int off = 1; off < 64; off <<= 1) {
    int u = __shfl_up(s, off);
    if (lane >= off) s += u;
  }
  if (lane == 63) wtot[w] = s;
  __syncthreads();
  int add = wpre[0] + wpre[1] + wpre[2] + wpre[3];
  for (int k = 0; k < w; ++k) add += wtot[k];
  if (i < N_NODES) {
    int excl = s - c + add;
    rowptr[i] = excl;
    cursor[i] = excl;
    invdeg[i] = 1.0f / (float)((c > 1) ? c : 1);
  }
  if (blockIdx.x == 0 && t == 0) rowptr[N_NODES] = N_EDGES;
}

__global__ __launch_bounds__(256) void k_fill(
    const int* __restrict__ ei, int* __restrict__ cursor, int* __restrict__ csr) {
  int e = blockIdx.x * 256 + threadIdx.x;
  if (e < N_EDGES) {
    int d = ei[N_EDGES + e];
    int p = atomicAdd(&cursor[d], 1);
    csr[p] = ei[e];
  }
}

// ---------------------------------------------------------------------------
// Gather-mean aggregation: 4 nodes/wave, 16 lanes x 16B (uint4) per edge,
// 4-wide unroll -> 16 outstanding loads/wave. Reads x-half, writes msg-half.
// ---------------------------------------------------------------------------
__global__ __launch_bounds__(256) void k_agg(
    unsigned* __restrict__ A, const int* __restrict__ rowptr,
    const int* __restrict__ csr, const float* __restrict__ invdeg) {
  const int wid = (blockIdx.x * 256 + threadIdx.x) >> 6;  // 0..12499
  const int lane = threadIdx.x & 63;
  const int sg = lane >> 4, l = lane & 15;
  const int node = wid * 4 + sg;                          // < 50000 exact
  const int beg = rowptr[node], end = rowptr[node + 1];
  const uint4* H4 = (const uint4*)A;  // row pitch 32 uint4; x-half at +16

  float s0[8] = {0,0,0,0,0,0,0,0}, s1[8] = {0,0,0,0,0,0,0,0};
  float s2[8] = {0,0,0,0,0,0,0,0}, s3[8] = {0,0,0,0,0,0,0,0};
  int j = beg;
  for (; j + 4 <= end; j += 4) {
    int c0 = csr[j], c1 = csr[j + 1], c2 = csr[j + 2], c3 = csr[j + 3];
    uint4 p0 = H4[(size_t)c0 * 32 + 16 + l];
    uint4 p1 = H4[(size_t)c1 * 32 + 16 + l];
    uint4 p2 = H4[(size_t)c2 * 32 + 16 + l];
    uint4 p3 = H4[(size_t)c3 * 32 + 16 + l];
    ACC8(s0, p0); ACC8(s1, p1); ACC8(s2, p2); ACC8(s3, p3);
  }
  if (j + 2 <= end) {
    int c0 = csr[j], c1 = csr[j + 1];
    uint4 p0 = H4[(size_t)c0 * 32 + 16 + l];
    uint4 p1 = H4[(size_t)c1 * 32 + 16 + l];
    ACC8(s0, p0); ACC8(s1, p1);
    j += 2;
  }
  if (j < end) {
    uint4 p0 = H4[(size_t)csr[j] * 32 + 16 + l];
    ACC8(s0, p0);
  }
  #pragma unroll
  for (int k = 0; k < 8; ++k) s0[k] += s1[k] + s2[k] + s3[k];

  const float rd = invdeg[node];
  uint4 o;
  o.x = (unsigned)f2b(s0[0] * rd) | ((unsigned)f2b(s0[1] * rd) << 16);
  o.y = (unsigned)f2b(s0[2] * rd) | ((unsigned)f2b(s0[3] * rd) << 16);
  o.z = (unsigned)f2b(s0[4] * rd) | ((unsigned)f2b(s0[5] * rd) << 16);
  o.w = (unsigned)f2b(s0[6] * rd) | ((unsigned)f2b(s0[7] * rd) << 16);
  ((uint4*)A)[(size_t)node * 32 + l] = o;
}

// ---------------------------------------------------------------------------
// Tile-parallel MFMA GEMM [16 x 256 @ 256x128] + bias + LN + GELU.
// Grid 3125. B-frag loads COALESCED via chunk-major WT layout.
// ---------------------------------------------------------------------------
__global__ __launch_bounds__(256) void k_gemm128(
    const unsigned short* __restrict__ Acat, const unsigned short* __restrict__ WT,
    const float* __restrict__ bl, const float* __restrict__ g,
    const float* __restrict__ be, unsigned short* __restrict__ Adst) {
  __shared__ __align__(16) char lds[8704];      // 8KB A-tile + 512B partials
  unsigned short* olds = (unsigned short*)lds;  // out-stage [16][136] (reuse)
  float2* pp = (float2*)(lds + 8192);           // [4 waves][16 rows] (s, sq)

  const int t = threadIdx.x;
  const int rw = blockIdx.x * 16;
  const int wave = t >> 6, lane = t & 63;
  const int lr = lane & 15, lg = lane >> 4;

  #pragma unroll
  for (int it = 0; it < 2; ++it) {
    int id = it * 256 + t;
    int r = id >> 5, c = id & 31;
    sh8 v = *(const sh8*)(Acat + (size_t)(rw + r) * KK + c * 8);
    unsigned off = (unsigned)((r * 512 + c * 16) ^ ((r & 7) << 4));
    *(sh8*)(lds + off) = v;
  }

  sh8 Bfrag[2][8];
  {
    const sh8* Bp = (const sh8*)WT;  // [32 chunks][128 n]
    #pragma unroll
    for (int fl = 0; fl < 2; ++fl) {
      const int n = wave * 32 + fl * 16 + lr;
      #pragma unroll
      for (int ks = 0; ks < 8; ++ks) Bfrag[fl][ks] = Bp[(ks * 4 + lg) * 128 + n];
    }
  }
  const int col0 = wave * 32 + lr, col1 = col0 + 16;
  const float bc0 = bl[col0], bc1 = bl[col1];
  const float gv0 = g[col0], gv1 = g[col1];
  const float bev0 = be[col0], bev1 = be[col1];

  __syncthreads();

  f32x4 acc0 = {0.f, 0.f, 0.f, 0.f}, acc1 = {0.f, 0.f, 0.f, 0.f};
  #pragma unroll
  for (int ks = 0; ks < 8; ++ks) {
    unsigned off = (unsigned)((lr * 512 + ks * 64 + lg * 16) ^ ((lr & 7) << 4));
    sh8 a = *(const sh8*)(lds + off);
    acc0 = __builtin_amdgcn_mfma_f32_16x16x32_bf16(a, Bfrag[0][ks], acc0, 0, 0, 0);
    acc1 = __builtin_amdgcn_mfma_f32_16x16x32_bf16(a, Bfrag[1][ks], acc1, 0, 0, 0);
  }

  float sv[4], qv[4];
  #pragma unroll
  for (int r = 0; r < 4; ++r) {
    float v0 = acc0[r] + bc0, v1 = acc1[r] + bc1;
    acc0[r] = v0; acc1[r] = v1;
    sv[r] = v0 + v1; qv[r] = v0 * v0 + v1 * v1;
  }
  #pragma unroll
  for (int m = 1; m < 16; m <<= 1) {
    #pragma unroll
    for (int r = 0; r < 4; ++r) {
      sv[r] += __shfl_xor(sv[r], m);
      qv[r] += __shfl_xor(qv[r], m);
    }
  }
  if (lr == 0) {
    #pragma unroll
    for (int r = 0; r < 4; ++r)
      pp[wave * 16 + lg * 4 + r] = make_float2(sv[r], qv[r]);
  }
  __syncthreads();

  #pragma unroll
  for (int r = 0; r < 4; ++r) {
    const int row = lg * 4 + r;
    float2 a0 = pp[row], a1 = pp[16 + row], a2 = pp[32 + row], a3 = pp[48 + row];
    float mu = (a0.x + a1.x + a2.x + a3.x) * (1.0f / 128.0f);
    float var = (a0.y + a1.y + a2.y + a3.y) * (1.0f / 128.0f) - mu * mu;
    float rs = rsqrtf(var + EPSN);
    float xn0 = (acc0[r] - mu) * rs * gv0 + bev0;
    float xn1 = (acc1[r] - mu) * rs * gv1 + bev1;
    olds[row * 136 + col0] = f2b(gelu_f(xn0));
    olds[row * 136 + col1] = f2b(gelu_f(xn1));
  }
  __syncthreads();

  {
    int r = t >> 4, c = t & 15;
    sh8 v = *(const sh8*)((char*)olds + r * 272 + c * 16);
    *(sh8*)(Adst + (size_t)(rw + r) * KK + 128 + c * 8) = v;
  }
}

// ---------------------------------------------------------------------------
// Layer-2 projection: PQ = h1 @ [Wl2|Wr2]  ([50000x128] @ [128x80], bf16 out).
// ---------------------------------------------------------------------------
__global__ __launch_bounds__(256) void k_gemm80(
    const unsigned short* __restrict__ Acat, const unsigned short* __restrict__ WT2b,
    unsigned short* __restrict__ PQ) {
  __shared__ __align__(16) char lds[16384];
  const int t = threadIdx.x;
  const int rw = blockIdx.x * 64;
  const int wave = t >> 6, lane = t & 63;
  const int lr = lane & 15, lg = lane >> 4;

  #pragma unroll
  for (int it = 0; it < 4; ++it) {
    int id = it * 256 + t;
    int r = id >> 4, c = id & 15;
    int gr = rw + r; if (gr >= N_NODES) gr = N_NODES - 1;
    sh8 v = *(const sh8*)(Acat + (size_t)gr * KK + 128 + c * 8);
    unsigned off = (unsigned)((r * 256 + c * 16) ^ ((r & 7) << 4));
    *(sh8*)(lds + off) = v;
  }

  sh8 Bfrag[5][4];
  {
    const sh8* Bp = (const sh8*)WT2b;  // [16 chunks][80 n]
    #pragma unroll
    for (int f = 0; f < 5; ++f) {
      const int n = f * 16 + lr;
      #pragma unroll
      for (int ks = 0; ks < 4; ++ks) Bfrag[f][ks] = Bp[(ks * 4 + lg) * 80 + n];
    }
  }
  __syncthreads();

  f32x4 accs[5];
  #pragma unroll
  for (int f = 0; f < 5; ++f) accs[f] = (f32x4){0.f, 0.f, 0.f, 0.f};

  #pragma unroll
  for (int ks = 0; ks < 4; ++ks) {
    const int r = wave * 16 + lr;
    unsigned off = (unsigned)((r * 256 + ks * 64 + lg * 16) ^ ((r & 7) << 4));
    sh8 a = *(const sh8*)(lds + off);
    #pragma unroll
    for (int f = 0; f < 5; ++f)
      accs[f] = __builtin_amdgcn_mfma_f32_16x16x32_bf16(a, Bfrag[f][ks], accs[f], 0, 0, 0);
  }
  __syncthreads();

  unsigned short* olds = (unsigned short*)lds;
  #pragma unroll
  for (int f = 0; f < 5; ++f) {
    #pragma unroll
    for (int r = 0; r < 4; ++r) {
      const int row = wave * 16 + lg * 4 + r;
      olds[row * 80 + f * 16 + lr] = f2b(accs[f][r]);
    }
  }
  __syncthreads();

  #pragma unroll
  for (int it = 0; it < 3; ++it) {
    int id = it * 256 + t;
    if (id < 640) {
      int r = (id * 6554) >> 16;   // id / 10
      int c = id - r * 10;
      int gr = rw + r;
      if (gr < N_NODES)
        *(sh8*)(PQ + (size_t)gr * 80 + c * 8) =
            *(const sh8*)((char*)olds + r * 160 + c * 16);
    }
  }
}

// ---------------------------------------------------------------------------
// Final: per node, mean-gather P (40 dims) + Q + bias, log_softmax -> out.
// ---------------------------------------------------------------------------
__global__ __launch_bounds__(256) void k_final(
    const unsigned short* __restrict__ PQ, const float* __restrict__ bl,
    const int* __restrict__ rowptr, const int* __restrict__ csr,
    const float* __restrict__ invdeg, float* __restrict__ out) {
  const int node = blockIdx.x * 8 + (threadIdx.x >> 5);
  const int hl = threadIdx.x & 31;
  const bool act = (hl < 20);
  const int l = act ? hl : 0;
  const unsigned* Pu = (const unsigned*)PQ;  // row pitch 40 uints

  const int beg = rowptr[node], end = rowptr[node + 1];
  float ax = 0.f, ay = 0.f, bx = 0.f, by = 0.f;
  float cx = 0.f, cy = 0.f, dx = 0.f, dy = 0.f;
  int j = beg;
  for (; j + 4 <= end; j += 4) {
    int c0 = csr[j], c1 = csr[j + 1], c2 = csr[j + 2], c3 = csr[j + 3];
    unsigned p0 = Pu[(size_t)c0 * 40 + l];
    unsigned p1 = Pu[(size_t)c1 * 40 + l];
    unsigned p2 = Pu[(size_t)c2 * 40 + l];
    unsigned p3 = Pu[(size_t)c3 * 40 + l];
    ax += b2f((unsigned short)p0); ay += b2f((unsigned short)(p0 >> 16));
    bx += b2f((unsigned short)p1); by += b2f((unsigned short)(p1 >> 16));
    cx += b2f((unsigned short)p2); cy += b2f((unsigned short)(p2 >> 16));
    dx += b2f((unsigned short)p3); dy += b2f((unsigned short)(p3 >> 16));
  }
  for (; j < end; ++j) {
    unsigned p = Pu[(size_t)csr[j] * 40 + l];
    ax += b2f((unsigned short)p); ay += b2f((unsigned short)(p >> 16));
  }
  ax += bx + cx + dx;
  ay += by + cy + dy;
  const float rd = invdeg[node];
  unsigned q = Pu[(size_t)node * 40 + 20 + l];
  float v0 = ax * rd + b2f((unsigned short)q) + bl[2 * l];
  float v1 = ay * rd + b2f((unsigned short)(q >> 16)) + bl[2 * l + 1];

  float m = act ? fmaxf(v0, v1) : -INFINITY;
  #pragma unroll
  for (int k = 1; k < 32; k <<= 1) m = fmaxf(m, __shfl_xor(m, k));
  float se = act ? (expf(v0 - m) + expf(v1 - m)) : 0.0f;
  #pragma unroll
  for (int k = 1; k < 32; k <<= 1) se += __shfl_xor(se, k);
  float lse = m + logf(se);
  if (act)
    ((float2*)out)[(size_t)node * 20 + hl] = make_float2(v0 - lse, v1 - lse);
}

// ---------------------------------------------------------------------------
extern "C" void kernel_launch(void* const* d_in, const int* in_sizes, int n_in,
                              void* d_out, int out_size, void* d_ws, size_t ws_size,
                              hipStream_t stream) {
  const float* x   = (const float*)d_in[0];
  const int*   ei  = (const int*)d_in[1];
  const float* Wl0 = (const float*)d_in[2];
  const float* bl0 = (const float*)d_in[3];
  const float* Wr0 = (const float*)d_in[4];
  const float* Wl1 = (const float*)d_in[5];
  const float* bl1 = (const float*)d_in[6];
  const float* Wr1 = (const float*)d_in[7];
  const float* Wl2 = (const float*)d_in[8];
  const float* bl2 = (const float*)d_in[9];
  const float* Wr2 = (const float*)d_in[10];
  const float* g0  = (const float*)d_in[11];
  const float* be0 = (const float*)d_in[12];
  const float* g1  = (const float*)d_in[13];
  const float* be1 = (const float*)d_in[14];
  float* out = (float*)d_out;

  unsigned short* A    = (unsigned short*)d_ws;       // 50000*256 bf16 (25.6MB)
  unsigned short* PQ   = A + (size_t)N_NODES * KK;    // 50000*80 bf16 (8MB)
  unsigned short* WT0  = PQ + (size_t)N_NODES * 80;   // 128*256
  unsigned short* WT1  = WT0 + 128 * KK;              // 128*256
  unsigned short* WT2b = WT1 + 128 * KK;              // 80*128
  float* invdeg = (float*)(WT2b + 80 * 128);          // 50000
  int*   counts = (int*)(invdeg + N_NODES);           // 50000
  int*   rowptr = counts + N_NODES;                   // 50001
  int*   cursor = rowptr + N_NODES + 1;               // 50000
  int*   csr    = cursor + N_NODES;                   // 600000

  const int egrid = (N_EDGES + 255) / 256;    // 2344
  const int pgrid = 2344 + 12500 + 296;       // 15140
  const int agrid = N_NODES / 16;             // 3125 (4 waves x 4 nodes each)
  const int g128  = N_NODES / 16;             // 3125
  const int g80   = (N_NODES + 63) / 64;      // 782
  const int fgrid = N_NODES / 8;              // 6250

  // --- CSR build + converts ---
  hipMemsetAsync(counts, 0, N_NODES * sizeof(int), stream);
  k_prep<<<pgrid, 256, 0, stream>>>(ei, counts, x, (unsigned*)A,
                                    Wl0, Wr0, Wl1, Wr1, Wl2, Wr2,
                                    WT0, WT1, WT2b);
  k_rowptr<<<NB1, 256, 0, stream>>>(counts, rowptr, cursor, invdeg);
  k_fill<<<egrid, 256, 0, stream>>>(ei, cursor, csr);

  // --- Layer 0 ---
  k_agg<<<agrid, 256, 0, stream>>>((unsigned*)A, rowptr, csr, invdeg);
  k_gemm128<<<g128, 256, 0, stream>>>(A, WT0, bl0, g0, be0, A);

  // --- Layer 1 ---
  k_agg<<<agrid, 256, 0, stream>>>((unsigned*)A, rowptr, csr, invdeg);
  k_gemm128<<<g128, 256, 0, stream>>>(A, WT1, bl1, g1, be1, A);

  // --- Layer 2 (project to 40+40 dims, then gather in 40-dim space) ---
  k_gemm80<<<g80, 256, 0, stream>>>(A, WT2b, PQ);
  k_final<<<fgrid, 256, 0, stream>>>(PQ, bl2, rowptr, csr, invdeg, out);
}